// Round 8
// baseline (455.698 us; speedup 1.0000x reference)
//
#include <hip/hip_runtime.h>
#include <hip/hip_bf16.h>

typedef __hip_bfloat16 bf16;
typedef __attribute__((ext_vector_type(8))) short short8;
typedef __attribute__((ext_vector_type(4))) float floatx4;
typedef unsigned long long u64;

#define NVP 10242
#define NV  40962
#define NF  81920
#define FPF 4    // faces per wave in k_facegrad
#define VPB 16   // vertices per block in k_vertex
#define FROW 260 // feat row stride in shorts (520 B -> bank row*2%32, conflict-free)

__device__ __forceinline__ unsigned short f2bfbits(float f) {
    bf16 h = __float2bfloat16(f);
    return __builtin_bit_cast(unsigned short, h);
}
// fp8 e4m3 (OCP on gfx950)
__device__ __forceinline__ unsigned short pk_fp8(float a, float b) {
    int p = __builtin_amdgcn_cvt_pk_fp8_f32(a, b, 0, false);
    return (unsigned short)(p & 0xffff);
}
__device__ __forceinline__ unsigned char one_fp8(float a) {
    int p = __builtin_amdgcn_cvt_pk_fp8_f32(a, 0.f, 0, false);
    return (unsigned char)(p & 0xff);
}
__device__ __forceinline__ float f8s0(unsigned int u){return __builtin_amdgcn_cvt_f32_fp8(u,0);}
__device__ __forceinline__ float f8s1(unsigned int u){return __builtin_amdgcn_cvt_f32_fp8(u,1);}
__device__ __forceinline__ float f8s2(unsigned int u){return __builtin_amdgcn_cvt_f32_fp8(u,2);}
__device__ __forceinline__ float f8s3(unsigned int u){return __builtin_amdgcn_cvt_f32_fp8(u,3);}
__device__ __forceinline__ void unpack8(u64 v, float o[8]) {
    unsigned int lo = (unsigned int)v, hi = (unsigned int)(v >> 32);
    o[0]=f8s0(lo); o[1]=f8s1(lo); o[2]=f8s2(lo); o[3]=f8s3(lo);
    o[4]=f8s0(hi); o[5]=f8s1(hi); o[6]=f8s2(hi); o[7]=f8s3(hi);
}

// ---------------------------------------------------------------------------
// K0 (merged prep): blocks [0,64): coeffsB; [64,384): packG; [384,545): packV.
// Gpk per-face 128 B: dw[0..8] 9 cols | dw[16..24] 9 vals | dw[25..27] EW |
//                     dw[28..30] NS.
// Vpk per-vertex 112 B: dw[0..6] 7 Lcols | dw[7..12] 6 F2Vcols |
//                       dw[14..20] 7 Lvals | dw[21..26] 6 F2Vvals.
// ---------------------------------------------------------------------------
__global__ void k_prep(const float* __restrict__ coeffs,
                       unsigned short* __restrict__ coeffsB,
                       const int* __restrict__ G_cols,
                       const float* __restrict__ G_vals,
                       const float* __restrict__ EW,
                       const float* __restrict__ NS,
                       float* __restrict__ Gpk,
                       const int* __restrict__ L_cols,
                       const float* __restrict__ L_vals,
                       const int* __restrict__ F2V_cols,
                       const float* __restrict__ F2V_vals,
                       float* __restrict__ Vpk) {
    int b = blockIdx.x;
    if (b < 64) {
        int t = b * 256 + threadIdx.x;                 // 0..16383
        int j = t & 7, lane = (t >> 3) & 63, s = t >> 9;
        int ot = s >> 3, kk = s & 7;
        int o  = ot * 16 + (lane & 15);
        int kg = kk * 32 + (lane >> 4) * 8 + j;
        coeffsB[t] = f2bfbits(coeffs[o * 256 + kg]);
    } else if (b < 384) {
        int f = (b - 64) * 256 + threadIdx.x;          // NF/256 = 320 exact
        float r[32];
#pragma unroll
        for (int q = 0; q < 32; ++q) r[q] = 0.f;
#pragma unroll
        for (int d = 0; d < 3; ++d)
#pragma unroll
            for (int j = 0; j < 3; ++j) {
                int idx = (d * NF + f) * 3 + j;
                r[d * 3 + j]      = __int_as_float(G_cols[idx]);
                r[16 + d * 3 + j] = G_vals[idx];
            }
#pragma unroll
        for (int d = 0; d < 3; ++d) {
            r[25 + d] = EW[f * 3 + d];
            r[28 + d] = NS[f * 3 + d];
        }
        float4* dst = (float4*)(Gpk + (size_t)f * 32);
#pragma unroll
        for (int q = 0; q < 8; ++q) dst[q] = ((const float4*)r)[q];
    } else {
        int v = (b - 384) * 256 + threadIdx.x;
        if (v >= NV) return;
        float r[28];
#pragma unroll
        for (int q = 0; q < 28; ++q) r[q] = 0.f;
#pragma unroll
        for (int j = 0; j < 7; ++j) {
            r[j]      = __int_as_float(L_cols[v * 7 + j]);
            r[14 + j] = L_vals[v * 7 + j];
        }
#pragma unroll
        for (int j = 0; j < 6; ++j) {
            r[7 + j]  = __int_as_float(F2V_cols[v * 6 + j]);
            r[21 + j] = F2V_vals[v * 6 + j];
        }
        float4* dst = (float4*)(Vpk + (size_t)v * 28);
#pragma unroll
        for (int q = 0; q < 7; ++q) dst[q] = ((const float4*)r)[q];
    }
}

// ---------------------------------------------------------------------------
// K1: batch-packing transpose (R5 form, proven fast). x[b][c][v] fp32 ->
//   xinp [v][c][b0..7] bf16 (uint4/entry), xin8p [v][c][b0..7] fp8 (u64).
// All stores coalesced (u64 / uint4 at consecutive c).
// ---------------------------------------------------------------------------
__global__ void __launch_bounds__(256) k_transpose(
    const float* __restrict__ x,
    uint4* __restrict__ xinp, u64* __restrict__ xin8p) {
    __shared__ u64 t8 [32][65];
    __shared__ u64 tbL[32][65];
    __shared__ u64 tbH[32][65];
    int v0 = blockIdx.x * 64;
    int tx = threadIdx.x & 63, ty = threadIdx.x >> 6;  // ty 0..3
    for (int half = 0; half < 2; ++half) {
        if (half) __syncthreads();
#pragma unroll
        for (int r = 0; r < 8; ++r) {
            int c  = ty + r * 4;             // 0..31
            int cg = half * 32 + c;
            int v  = v0 + tx;
            u64 p8 = 0, bL = 0, bH = 0;
#pragma unroll
            for (int b = 0; b < 8; ++b) {
                float val = (v < NVP) ? x[((size_t)b * 64 + cg) * NVP + v] : 1.0f;
                p8 |= (u64)one_fp8(val) << (8 * b);
                u64 bf = (u64)f2bfbits(val);
                if (b < 4) bL |= bf << (16 * b);
                else       bH |= bf << (16 * (b - 4));
            }
            t8[c][tx] = p8; tbL[c][tx] = bL; tbH[c][tx] = bH;
        }
        __syncthreads();
        int cc = threadIdx.x & 31;
        int vq = threadIdx.x >> 5;           // 0..7
#pragma unroll
        for (int it = 0; it < 8; ++it) {
            int v  = vq * 8 + it;            // 0..63
            int vg = v0 + v;
            if (vg < NV) {
                size_t idx = (size_t)vg * 64 + half * 32 + cc;
                xin8p[idx] = t8[cc][v];
                u64 lo = tbL[cc][v], hi = tbH[cc][v];
                xinp[idx] = make_uint4((unsigned)lo, (unsigned)(lo >> 32),
                                       (unsigned)hi, (unsigned)(hi >> 32));
            }
        }
    }
}

// ---------------------------------------------------------------------------
// K2: face gradients (R5 form). All 8 batches per wave-face; FPF=4 -> 36 u64
// gathers in flight (R5 had 18). sched_barrier(0) pins them.
// Output gfip[f][c][b]: (ew|ns) fp8 pair x8 = uint4.
// ---------------------------------------------------------------------------
__global__ void __launch_bounds__(256, 4) k_facegrad(
    const u64* __restrict__ xin8p,
    const float* __restrict__ Gpk,
    uint4* __restrict__ gfip) {
    int w  = __builtin_amdgcn_readfirstlane(threadIdx.x >> 6);
    int c  = threadIdx.x & 63;
    int f0 = (blockIdx.x * 4 + w) * FPF;

    // stage A: scalar col loads
    int gc[FPF][9];
#pragma unroll
    for (int i = 0; i < FPF; ++i) {
        const int* ri = (const int*)(Gpk + (size_t)(f0 + i) * 32);
#pragma unroll
        for (int j = 0; j < 9; ++j) gc[i][j] = ri[j];
    }
    // stage B: all 36 u64 gathers in flight
    u64 xv[FPF][9];
#pragma unroll
    for (int i = 0; i < FPF; ++i)
#pragma unroll
        for (int j = 0; j < 9; ++j)
            xv[i][j] = xin8p[(size_t)gc[i][j] * 64 + c];
    __builtin_amdgcn_sched_barrier(0);
    // stage C: per-batch math + store
#pragma unroll
    for (int i = 0; i < FPF; ++i) {
        const float* rf = Gpk + (size_t)(f0 + i) * 32;
        float g0[8], g1[8], g2[8];
#pragma unroll
        for (int b = 0; b < 8; ++b) { g0[b] = 0.f; g1[b] = 0.f; g2[b] = 0.f; }
#pragma unroll
        for (int j = 0; j < 3; ++j) {
            float fa[8], fb[8], fd[8];
            unpack8(xv[i][j],     fa);
            unpack8(xv[i][3 + j], fb);
            unpack8(xv[i][6 + j], fd);
            float va = rf[16 + j], vb = rf[19 + j], vc = rf[22 + j];
#pragma unroll
            for (int b = 0; b < 8; ++b) {
                g0[b] += va * fa[b];
                g1[b] += vb * fb[b];
                g2[b] += vc * fd[b];
            }
        }
        float e0 = rf[25], e1 = rf[26], e2 = rf[27];
        float n0 = rf[28], n1 = rf[29], n2 = rf[30];
        unsigned int d[4] = {0u, 0u, 0u, 0u};
#pragma unroll
        for (int b = 0; b < 8; ++b) {
            float ew = g0[b] * e0 + g1[b] * e1 + g2[b] * e2;
            float ns = g0[b] * n0 + g1[b] * n1 + g2[b] * n2;
            d[b >> 1] |= (unsigned int)pk_fp8(ew, ns) << ((b & 1) * 16);
        }
        gfip[(size_t)(f0 + i) * 64 + c] = make_uint4(d[0], d[1], d[2], d[3]);
    }
}

// ---------------------------------------------------------------------------
// K3: packed vertex kernel, R5-defects fixed. 512 thr, 16 vertices/block,
// 8 waves; wave w handles 2 vertices -> 28 wide CONTIGUOUS loads in flight
// (uint4/u64 rows; R7's narrow-strided extraction is the proven anti-pattern).
// feat: 128 (v,b) rows x 260 shorts = 66.6 KB; outs ALIASED into feat after
// a sync -> 2 blocks/CU (4 waves/SIMD). launch_bounds(512,4) caps VGPR 128.
// MFMA: 128 rows x 64 o; wave w -> o-tile w&3, row-quarter w>>2 (32 MFMA).
// Epilogue: 16 consecutive v -> 64-B (full-sector) stores.
// ---------------------------------------------------------------------------
__global__ void __launch_bounds__(512, 4) k_vertex(
    const uint4* __restrict__ xinp,
    const u64* __restrict__ xin8p,
    const float* __restrict__ Vpk,
    const uint4* __restrict__ gfip,
    const unsigned short* __restrict__ coeffsB,
    const float* __restrict__ bias,
    float* __restrict__ out) {
    int vb = blockIdx.x * VPB;
    __shared__ unsigned short feat[128 * FROW];   // 66560 B
    float* outs = (float*)feat;                   // aliased: 128*65*4 = 33280 B
    int w = __builtin_amdgcn_readfirstlane(threadIdx.x >> 6);  // 0..7
    int c = threadIdx.x & 63;

    int vcs[2];
#pragma unroll
    for (int i = 0; i < 2; ++i) {
        int v = vb + w * 2 + i;
        vcs[i] = __builtin_amdgcn_readfirstlane(v < NV ? v : NV - 1);
    }
    // stage A: scalar col loads
    int lc[2][7], fc[2][6];
#pragma unroll
    for (int i = 0; i < 2; ++i) {
        const int* ri = (const int*)(Vpk + (size_t)vcs[i] * 28);
#pragma unroll
        for (int j = 0; j < 7; ++j) lc[i][j] = ri[j];
#pragma unroll
        for (int j = 0; j < 6; ++j) fc[i][j] = ri[7 + j];
    }
    // stage B: all 28 wide gathers in flight
    uint4 f0q[2], gq[2][6];
    u64 xl[2][7];
#pragma unroll
    for (int i = 0; i < 2; ++i) {
        f0q[i] = xinp[(size_t)vcs[i] * 64 + c];
#pragma unroll
        for (int j = 0; j < 7; ++j)
            xl[i][j] = xin8p[(size_t)lc[i][j] * 64 + c];
#pragma unroll
        for (int j = 0; j < 6; ++j)
            gq[i][j] = gfip[(size_t)fc[i][j] * 64 + c];
    }
    __builtin_amdgcn_sched_barrier(0);
    // stage C: per-vertex, per-batch math -> feat rows (vloc*8+b)
#pragma unroll
    for (int i = 0; i < 2; ++i) {
        const float* rv = Vpk + (size_t)vcs[i] * 28;
        float lap[8], ew[8], ns[8];
#pragma unroll
        for (int b = 0; b < 8; ++b) { lap[b] = 0.f; ew[b] = 0.f; ns[b] = 0.f; }
#pragma unroll
        for (int j = 0; j < 7; ++j) {
            float xa[8];
            unpack8(xl[i][j], xa);
            float lv = rv[14 + j];
#pragma unroll
            for (int b = 0; b < 8; ++b) lap[b] += lv * xa[b];
        }
#pragma unroll
        for (int j = 0; j < 6; ++j) {
            float val = rv[21 + j];
            unsigned int q0 = gq[i][j].x, q1 = gq[i][j].y;
            unsigned int q2 = gq[i][j].z, q3 = gq[i][j].w;
            ew[0] += val * f8s0(q0); ns[0] += val * f8s1(q0);
            ew[1] += val * f8s2(q0); ns[1] += val * f8s3(q0);
            ew[2] += val * f8s0(q1); ns[2] += val * f8s1(q1);
            ew[3] += val * f8s2(q1); ns[3] += val * f8s3(q1);
            ew[4] += val * f8s0(q2); ns[4] += val * f8s1(q2);
            ew[5] += val * f8s2(q2); ns[5] += val * f8s3(q2);
            ew[6] += val * f8s0(q3); ns[6] += val * f8s1(q3);
            ew[7] += val * f8s2(q3); ns[7] += val * f8s3(q3);
        }
        unsigned int fd[4] = {f0q[i].x, f0q[i].y, f0q[i].z, f0q[i].w};
        int vloc = w * 2 + i;
#pragma unroll
        for (int b = 0; b < 8; ++b) {
            unsigned short f0s = (unsigned short)(fd[b >> 1] >> ((b & 1) * 16));
            ushort4 p = make_ushort4(f0s, f2bfbits(lap[b]),
                                     f2bfbits(ew[b]), f2bfbits(ns[b]));
            *(ushort4*)&feat[(vloc * 8 + b) * FROW + c * 4] = p;
        }
    }
    __syncthreads();

    // ---- phase 2: MFMA. wave w: o-tile = w&3, row-quarter = w>>2 ----
    int m = c & 15, quad = c >> 4;
    int ot = w & 3, rg = w >> 2;
    float bo = bias[ot * 16 + m];
    floatx4 acc[4] = {{bo,bo,bo,bo},{bo,bo,bo,bo},{bo,bo,bo,bo},{bo,bo,bo,bo}};
#pragma unroll
    for (int t = 0; t < 4; ++t)
#pragma unroll
        for (int kk = 0; kk < 8; ++kk) {
            short8 a = *(const short8*)
                &feat[((rg * 4 + t) * 16 + m) * FROW + kk * 32 + quad * 8];
            short8 bfr = *(const short8*)&coeffsB[((ot * 8 + kk) * 64 + c) * 8];
            acc[t] = __builtin_amdgcn_mfma_f32_16x16x32_bf16(a, bfr, acc[t], 0, 0, 0);
        }
    __syncthreads();   // all feat reads done before outs overwrites it

    // C layout: col=lane&15 (o), row=quad*4+reg ((v,b) row)
#pragma unroll
    for (int t = 0; t < 4; ++t)
#pragma unroll
        for (int r = 0; r < 4; ++r)
            outs[((rg * 4 + t) * 16 + quad * 4 + r) * 65 + ot * 16 + m] = acc[t][r];
    __syncthreads();

    // ---- epilogue: out[b][o][vb..vb+15] -> 64-B contiguous stores ----
    int vp = threadIdx.x & 15;
    int oh = threadIdx.x >> 4;           // 0..31
    if (vb + vp < NV) {
#pragma unroll
        for (int s = 0; s < 2; ++s) {
            int o = oh + s * 32;
#pragma unroll
            for (int b = 0; b < 8; ++b)
                out[((size_t)b * 64 + o) * NV + vb + vp] =
                    outs[(vp * 8 + b) * 65 + o];
        }
    }
}

// ---------------------------------------------------------------------------
extern "C" void kernel_launch(void* const* d_in, const int* in_sizes, int n_in,
                              void* d_out, int out_size, void* d_ws, size_t ws_size,
                              hipStream_t stream) {
    const float* x        = (const float*)d_in[0];
    const int*   G_cols   = (const int*)  d_in[2];
    const float* G_vals   = (const float*)d_in[3];
    const int*   L_cols   = (const int*)  d_in[5];
    const float* L_vals   = (const float*)d_in[6];
    const int*   F2V_cols = (const int*)  d_in[8];
    const float* F2V_vals = (const float*)d_in[9];
    const float* EW       = (const float*)d_in[10];
    const float* NS       = (const float*)d_in[11];
    const float* coeffs   = (const float*)d_in[12];
    const float* bias     = (const float*)d_in[13];
    float* out = (float*)d_out;

    char* ws = (char*)d_ws;
    const size_t gpk_bytes  = (size_t)NF * 128;          // 10,485,760
    const size_t vpk_bytes  = (size_t)NV * 112;          //  4,587,744
    const size_t xinp_bytes = (size_t)NV * 64 * 16;      // 41,945,088
    const size_t x8p_bytes  = (size_t)NV * 64 * 8;       // 20,972,544
    // gfip = NF*64*16 = 83,886,080; total = 161,942,752 B (proven fit)

    unsigned short* coeffsB = (unsigned short*)ws;                    // 32 KB
    float* Gpk   = (float*)(ws + 65536);
    float* Vpk   = (float*)(ws + 65536 + gpk_bytes);
    uint4* xinp  = (uint4*)(ws + 65536 + gpk_bytes + vpk_bytes);
    u64*   xin8p = (u64*)  (ws + 65536 + gpk_bytes + vpk_bytes + xinp_bytes);
    uint4* gfip  = (uint4*)(ws + 65536 + gpk_bytes + vpk_bytes + xinp_bytes
                               + x8p_bytes);

    k_prep<<<545, 256, 0, stream>>>(coeffs, coeffsB, G_cols, G_vals, EW, NS,
                                    Gpk, L_cols, L_vals, F2V_cols, F2V_vals,
                                    Vpk);
    k_transpose<<<641, 256, 0, stream>>>(x, xinp, xin8p);
    k_facegrad<<<NF / (4 * FPF), 256, 0, stream>>>(xin8p, Gpk, gfip);
    k_vertex<<<(NV + VPB - 1) / VPB, 512, 0, stream>>>(
        xinp, xin8p, Vpk, gfip, coeffsB, bias, out);
}

// Round 9
// 362.268 us; speedup vs baseline: 1.2579x; 1.2579x over previous
//
#include <hip/hip_runtime.h>
#include <hip/hip_bf16.h>

typedef __hip_bfloat16 bf16;
typedef __attribute__((ext_vector_type(8))) short short8;
typedef __attribute__((ext_vector_type(4))) float floatx4;
typedef unsigned long long u64;

#define NVP 10242
#define NV  40962
#define NF  81920
#define VPB 32
#define FPF 2   // faces per wave, packed facegrad (tier A)
#define FPW 4   // faces per wave, per-batch facegrad (tier B, R4 form)

__device__ __forceinline__ unsigned short f2bfbits(float f) {
    bf16 h = __float2bfloat16(f);
    return __builtin_bit_cast(unsigned short, h);
}
// fp8 e4m3 (OCP on gfx950)
__device__ __forceinline__ unsigned short pk_fp8(float a, float b) {
    int p = __builtin_amdgcn_cvt_pk_fp8_f32(a, b, 0, false);
    return (unsigned short)(p & 0xffff);
}
__device__ __forceinline__ unsigned char one_fp8(float a) {
    int p = __builtin_amdgcn_cvt_pk_fp8_f32(a, 0.f, 0, false);
    return (unsigned char)(p & 0xff);
}
__device__ __forceinline__ float f8s0(unsigned int u){return __builtin_amdgcn_cvt_f32_fp8(u,0);}
__device__ __forceinline__ float f8s1(unsigned int u){return __builtin_amdgcn_cvt_f32_fp8(u,1);}
__device__ __forceinline__ float f8s2(unsigned int u){return __builtin_amdgcn_cvt_f32_fp8(u,2);}
__device__ __forceinline__ float f8s3(unsigned int u){return __builtin_amdgcn_cvt_f32_fp8(u,3);}
__device__ __forceinline__ void unpack8(u64 v, float o[8]) {
    unsigned int lo = (unsigned int)v, hi = (unsigned int)(v >> 32);
    o[0]=f8s0(lo); o[1]=f8s1(lo); o[2]=f8s2(lo); o[3]=f8s3(lo);
    o[4]=f8s0(hi); o[5]=f8s1(hi); o[6]=f8s2(hi); o[7]=f8s3(hi);
}

// ---------------------------------------------------------------------------
// K0 (merged prep): blocks [0,64): coeffsB; [64,384): packG; [384,545): packV.
// Gpk per-face 128 B: dw[0..8] 9 cols | dw[16..24] 9 vals | dw[25..27] EW |
//                     dw[28..30] NS.
// Vpk per-vertex 112 B: dw[0..6] 7 Lcols | dw[7..12] 6 F2Vcols |
//                       dw[14..20] 7 Lvals | dw[21..26] 6 F2Vvals.
// ---------------------------------------------------------------------------
__global__ void k_prep(const float* __restrict__ coeffs,
                       unsigned short* __restrict__ coeffsB,
                       const int* __restrict__ G_cols,
                       const float* __restrict__ G_vals,
                       const float* __restrict__ EW,
                       const float* __restrict__ NS,
                       float* __restrict__ Gpk,
                       const int* __restrict__ L_cols,
                       const float* __restrict__ L_vals,
                       const int* __restrict__ F2V_cols,
                       const float* __restrict__ F2V_vals,
                       float* __restrict__ Vpk) {
    int b = blockIdx.x;
    if (b < 64) {
        int t = b * 256 + threadIdx.x;                 // 0..16383
        int j = t & 7, lane = (t >> 3) & 63, s = t >> 9;
        int ot = s >> 3, kk = s & 7;
        int o  = ot * 16 + (lane & 15);
        int kg = kk * 32 + (lane >> 4) * 8 + j;
        coeffsB[t] = f2bfbits(coeffs[o * 256 + kg]);
    } else if (b < 384) {
        int f = (b - 64) * 256 + threadIdx.x;          // NF/256 = 320 exact
        float r[32];
#pragma unroll
        for (int q = 0; q < 32; ++q) r[q] = 0.f;
#pragma unroll
        for (int d = 0; d < 3; ++d)
#pragma unroll
            for (int j = 0; j < 3; ++j) {
                int idx = (d * NF + f) * 3 + j;
                r[d * 3 + j]      = __int_as_float(G_cols[idx]);
                r[16 + d * 3 + j] = G_vals[idx];
            }
#pragma unroll
        for (int d = 0; d < 3; ++d) {
            r[25 + d] = EW[f * 3 + d];
            r[28 + d] = NS[f * 3 + d];
        }
        float4* dst = (float4*)(Gpk + (size_t)f * 32);
#pragma unroll
        for (int q = 0; q < 8; ++q) dst[q] = ((const float4*)r)[q];
    } else {
        int v = (b - 384) * 256 + threadIdx.x;
        if (v >= NV) return;
        float r[28];
#pragma unroll
        for (int q = 0; q < 28; ++q) r[q] = 0.f;
#pragma unroll
        for (int j = 0; j < 7; ++j) {
            r[j]      = __int_as_float(L_cols[v * 7 + j]);
            r[14 + j] = L_vals[v * 7 + j];
        }
#pragma unroll
        for (int j = 0; j < 6; ++j) {
            r[7 + j]  = __int_as_float(F2V_cols[v * 6 + j]);
            r[21 + j] = F2V_vals[v * 6 + j];
        }
        float4* dst = (float4*)(Vpk + (size_t)v * 28);
#pragma unroll
        for (int q = 0; q < 7; ++q) dst[q] = ((const float4*)r)[q];
    }
}

// ---------------------------------------------------------------------------
// K1: merged transpose. x[b][c][v] fp32 (all 8 b) ->
//   per-batch xin[b][v][c] bf16, per-batch xin8[b][v][c] fp8,
//   and (tier A) packed xin8p[v][c][b0..7] u64 for the packed facegrad.
// Phase 2 writes full-wave v-rows: xin 128 B, xin8 64 B, xin8p 512 B runs.
// ---------------------------------------------------------------------------
__global__ void __launch_bounds__(256) k_transpose(
    const float* __restrict__ x,
    unsigned short* __restrict__ xin,
    unsigned char* __restrict__ xin8,
    u64* __restrict__ xin8p, int writeP8) {
    __shared__ u64 t8 [32][65];
    __shared__ u64 tbL[32][65];
    __shared__ u64 tbH[32][65];
    int v0 = blockIdx.x * 64;
    int tx = threadIdx.x & 63, ty = threadIdx.x >> 6;  // ty 0..3
    for (int half = 0; half < 2; ++half) {
        if (half) __syncthreads();
#pragma unroll
        for (int r = 0; r < 8; ++r) {
            int c  = ty + r * 4;             // 0..31
            int cg = half * 32 + c;
            int v  = v0 + tx;
            u64 p8 = 0, bL = 0, bH = 0;
#pragma unroll
            for (int b = 0; b < 8; ++b) {
                float val = (v < NVP) ? x[((size_t)b * 64 + cg) * NVP + v] : 1.0f;
                p8 |= (u64)one_fp8(val) << (8 * b);
                u64 bf = (u64)f2bfbits(val);
                if (b < 4) bL |= bf << (16 * b);
                else       bH |= bf << (16 * (b - 4));
            }
            t8[c][tx] = p8; tbL[c][tx] = bL; tbH[c][tx] = bH;
        }
        __syncthreads();
        int cc = threadIdx.x & 31;
        int vq = threadIdx.x >> 5;           // 0..7
#pragma unroll
        for (int it = 0; it < 8; ++it) {
            int v  = vq * 8 + it;            // 0..63
            int vg = v0 + v;
            if (vg < NV) {
                size_t idx = (size_t)vg * 64 + half * 32 + cc;
                u64 p8 = t8[cc][v], lo = tbL[cc][v], hi = tbH[cc][v];
                if (writeP8) xin8p[idx] = p8;
#pragma unroll
                for (int b = 0; b < 8; ++b) {
                    u64 src = (b < 4) ? lo : hi;
                    xin [(size_t)b * NV * 64 + idx] =
                        (unsigned short)(src >> (16 * (b & 3)));
                    xin8[(size_t)b * NV * 64 + idx] =
                        (unsigned char)(p8 >> (8 * b));
                }
            }
        }
    }
}

// ---------------------------------------------------------------------------
// K2a (tier A): packed facegrad. 9 u64 fp8 gathers/face serve all 8 batches
// (R5's proven gather side; 18 staged -> ~70 live VGPR, no spill). Output:
// per-batch gfi (R4's consumer layout) via 8 coalesced 128-B u16 row stores.
// ---------------------------------------------------------------------------
__global__ void __launch_bounds__(256, 4) k_facegrad_p(
    const u64* __restrict__ xin8p,
    const float* __restrict__ Gpk,
    unsigned short* __restrict__ gfi) {
    int w  = __builtin_amdgcn_readfirstlane(threadIdx.x >> 6);
    int c  = threadIdx.x & 63;
    int f0 = (blockIdx.x * 4 + w) * FPF;

    // stage A: scalar col loads
    int gc[FPF][9];
#pragma unroll
    for (int i = 0; i < FPF; ++i) {
        const int* ri = (const int*)(Gpk + (size_t)(f0 + i) * 32);
#pragma unroll
        for (int j = 0; j < 9; ++j) gc[i][j] = ri[j];
    }
    // stage B: all 18 u64 gathers in flight
    u64 xv[FPF][9];
#pragma unroll
    for (int i = 0; i < FPF; ++i)
#pragma unroll
        for (int j = 0; j < 9; ++j)
            xv[i][j] = xin8p[(size_t)gc[i][j] * 64 + c];
    __builtin_amdgcn_sched_barrier(0);
    // stage C: per-batch math + 8 coalesced per-batch stores
#pragma unroll
    for (int i = 0; i < FPF; ++i) {
        const float* rf = Gpk + (size_t)(f0 + i) * 32;
        float g0[8], g1[8], g2[8];
#pragma unroll
        for (int b = 0; b < 8; ++b) { g0[b] = 0.f; g1[b] = 0.f; g2[b] = 0.f; }
#pragma unroll
        for (int j = 0; j < 3; ++j) {
            float fa[8], fb[8], fd[8];
            unpack8(xv[i][j],     fa);
            unpack8(xv[i][3 + j], fb);
            unpack8(xv[i][6 + j], fd);
            float va = rf[16 + j], vb = rf[19 + j], vc = rf[22 + j];
#pragma unroll
            for (int b = 0; b < 8; ++b) {
                g0[b] += va * fa[b];
                g1[b] += vb * fb[b];
                g2[b] += vc * fd[b];
            }
        }
        float e0 = rf[25], e1 = rf[26], e2 = rf[27];
        float n0 = rf[28], n1 = rf[29], n2 = rf[30];
#pragma unroll
        for (int b = 0; b < 8; ++b) {
            float ew = g0[b] * e0 + g1[b] * e1 + g2[b] * e2;
            float ns = g0[b] * n0 + g1[b] * n1 + g2[b] * n2;
            gfi[(size_t)b * NF * 64 + (size_t)(f0 + i) * 64 + c] =
                pk_fp8(ew, ns);
        }
    }
}

// ---------------------------------------------------------------------------
// K2b (tier B fallback): R4's per-batch facegrad, verbatim (proven).
// ---------------------------------------------------------------------------
__global__ void __launch_bounds__(256, 4) k_facegrad_b(
    const unsigned char* __restrict__ xin8,
    const float* __restrict__ Gpk,
    unsigned short* __restrict__ gfi) {
    int batch = blockIdx.x & 7;
    int fblk  = blockIdx.x >> 3;
    xin8 += (size_t)batch * 64 * NV;
    gfi  += (size_t)batch * 64 * NF;
    int w  = __builtin_amdgcn_readfirstlane(threadIdx.x >> 6);
    int c  = threadIdx.x & 63;
    int f0 = (fblk * 4 + w) * FPW;

    int gc[FPW][9];
#pragma unroll
    for (int i = 0; i < FPW; ++i) {
        const int* ri = (const int*)(Gpk + (size_t)(f0 + i) * 32);
#pragma unroll
        for (int j = 0; j < 9; ++j) gc[i][j] = ri[j];
    }
    unsigned int xv[FPW][9];
#pragma unroll
    for (int i = 0; i < FPW; ++i)
#pragma unroll
        for (int j = 0; j < 9; ++j)
            xv[i][j] = xin8[(size_t)gc[i][j] * 64 + c];
    __builtin_amdgcn_sched_barrier(0);
#pragma unroll
    for (int i = 0; i < FPW; ++i) {
        const float* rf = Gpk + (size_t)(f0 + i) * 32;
        float g0 = rf[16] * f8s0(xv[i][0]) + rf[17] * f8s0(xv[i][1])
                 + rf[18] * f8s0(xv[i][2]);
        float g1 = rf[19] * f8s0(xv[i][3]) + rf[20] * f8s0(xv[i][4])
                 + rf[21] * f8s0(xv[i][5]);
        float g2 = rf[22] * f8s0(xv[i][6]) + rf[23] * f8s0(xv[i][7])
                 + rf[24] * f8s0(xv[i][8]);
        float ew = g0 * rf[25] + g1 * rf[26] + g2 * rf[27];
        float ns = g0 * rf[28] + g1 * rf[29] + g2 * rf[30];
        gfi[(f0 + i) * 64 + c] = pk_fp8(ew, ns);
    }
}

// ---------------------------------------------------------------------------
// K3: vertex kernel — R4 structure verbatim (proven 91 µs). 512 thr,
// 32 v/block, batch = bid&7 ≡ XCD (xin8 2.6 MB + gfi 10.5 MB per-XCD
// residency). 3-stage SoA: cols -> 56 gathers in flight -> math.
// Phase 2: wave (ot,vh) MFMA. Epilogue: 128-B line stores.
// ---------------------------------------------------------------------------
__global__ void __launch_bounds__(512, 2) k_vertex(
    const unsigned short* __restrict__ xin,
    const unsigned char* __restrict__ xin8,
    const float* __restrict__ Vpk,
    const unsigned short* __restrict__ gfi,
    const unsigned short* __restrict__ coeffsB,
    const float* __restrict__ bias,
    float* __restrict__ out) {
    int batch = blockIdx.x & 7;
    int vb    = (blockIdx.x >> 3) * VPB;
    xin  += (size_t)batch * 64 * NV;
    xin8 += (size_t)batch * 64 * NV;
    gfi  += (size_t)batch * 64 * NF;
    out  += (size_t)batch * 64 * NV;

    __shared__ unsigned short feat[VPB * 264];   // 16896 B
    __shared__ float outs[VPB * 65];             // 8320 B
    int w    = __builtin_amdgcn_readfirstlane(threadIdx.x >> 6);  // 0..7
    int lane = threadIdx.x & 63;
    int c    = lane;

    int vcs[4];
#pragma unroll
    for (int i = 0; i < 4; ++i) {
        int v = vb + w * 4 + i;
        vcs[i] = __builtin_amdgcn_readfirstlane(v < NV ? v : NV - 1);
    }
    // stage A: scalar col loads
    int lc[4][7], fc[4][6];
#pragma unroll
    for (int i = 0; i < 4; ++i) {
        const int* ri = (const int*)(Vpk + (size_t)vcs[i] * 28);
#pragma unroll
        for (int j = 0; j < 7; ++j) lc[i][j] = ri[j];
#pragma unroll
        for (int j = 0; j < 6; ++j) fc[i][j] = ri[7 + j];
    }
    // stage B: issue ALL 56 vector gathers
    unsigned int f0u[4], xl[4][7], gg[4][6];
#pragma unroll
    for (int i = 0; i < 4; ++i) {
        f0u[i] = xin[(size_t)vcs[i] * 64 + c];
#pragma unroll
        for (int j = 0; j < 7; ++j)
            xl[i][j] = xin8[(size_t)lc[i][j] * 64 + c];
#pragma unroll
        for (int j = 0; j < 6; ++j)
            gg[i][j] = gfi[(size_t)fc[i][j] * 64 + c];
    }
    __builtin_amdgcn_sched_barrier(0);
    // stage C: val loads + math + feat store
#pragma unroll
    for (int i = 0; i < 4; ++i) {
        const float* rv = Vpk + (size_t)vcs[i] * 28;
        float lap = 0.f;
#pragma unroll
        for (int j = 0; j < 7; ++j)
            lap += rv[14 + j] * f8s0(xl[i][j]);
        float ew = 0.f, ns = 0.f;
#pragma unroll
        for (int j = 0; j < 6; ++j) {
            float val = rv[21 + j];
            ew += val * f8s0(gg[i][j]);
            ns += val * f8s1(gg[i][j]);
        }
        ushort4 p = make_ushort4((unsigned short)f0u[i], f2bfbits(lap),
                                 f2bfbits(ew), f2bfbits(ns));
        *(ushort4*)&feat[(w * 4 + i) * 264 + c * 4] = p;  // 8B, 2-way (free)
    }
    __syncthreads();

    // ---- phase 2: MFMA. wave w: o-tile = w&3, v-half = w>>2 ----
    int m = lane & 15, quad = lane >> 4;
    int ot = w & 3, vh = w >> 2;
    float bo = bias[ot * 16 + m];
    floatx4 acc = {bo, bo, bo, bo};
#pragma unroll
    for (int kk = 0; kk < 8; ++kk) {
        short8 a = *(const short8*)&feat[(vh * 16 + m) * 264 + kk * 32 + quad * 8];
        short8 bfr = *(const short8*)&coeffsB[((ot * 8 + kk) * 64 + lane) * 8];
        acc = __builtin_amdgcn_mfma_f32_16x16x32_bf16(a, bfr, acc, 0, 0, 0);
    }

    // ---- epilogue: C layout col=lane&15 (o), row=quad*4+reg (v) ----
#pragma unroll
    for (int r2 = 0; r2 < 4; ++r2)
        outs[(vh * 16 + quad * 4 + r2) * 65 + ot * 16 + m] = acc[r2];
    __syncthreads();
    int vp = threadIdx.x & 31;          // 32 consecutive v -> 128 B lines
    int og = threadIdx.x >> 5;          // 0..15
    if (vb + vp < NV) {
#pragma unroll
        for (int r2 = 0; r2 < 4; ++r2) {
            int o2 = og + r2 * 16;
            out[(size_t)o2 * NV + vb + vp] = outs[vp * 65 + o2];
        }
    }
}

// ---------------------------------------------------------------------------
extern "C" void kernel_launch(void* const* d_in, const int* in_sizes, int n_in,
                              void* d_out, int out_size, void* d_ws, size_t ws_size,
                              hipStream_t stream) {
    const float* x        = (const float*)d_in[0];
    const int*   G_cols   = (const int*)  d_in[2];
    const float* G_vals   = (const float*)d_in[3];
    const int*   L_cols   = (const int*)  d_in[5];
    const float* L_vals   = (const float*)d_in[6];
    const int*   F2V_cols = (const int*)  d_in[8];
    const float* F2V_vals = (const float*)d_in[9];
    const float* EW       = (const float*)d_in[10];
    const float* NS       = (const float*)d_in[11];
    const float* coeffs   = (const float*)d_in[12];
    const float* bias     = (const float*)d_in[13];
    float* out = (float*)d_out;

    char* ws = (char*)d_ws;
    const size_t gpk_bytes  = (size_t)NF * 128;          // 10,485,760
    const size_t vpk_bytes  = (size_t)NV * 112;          //  4,587,744
    const size_t xin_bytes  = (size_t)8 * NV * 64 * 2;   // 41,945,088
    const size_t x8_bytes   = (size_t)8 * NV * 64;       // 20,972,544
    const size_t gfi_bytes  = (size_t)8 * NF * 64 * 2;   // 83,886,080
    const size_t x8p_bytes  = (size_t)NV * 64 * 8;       // 20,972,544
    size_t base  = 65536 + gpk_bytes + vpk_bytes + xin_bytes + x8_bytes
                 + gfi_bytes;                            // 161,942,752 (proven)
    size_t needA = base + x8p_bytes;                     // 182,915,296
    int tierA = (ws_size >= needA) ? 1 : 0;

    unsigned short* coeffsB = (unsigned short*)ws;                    // 32 KB
    float* Gpk = (float*)(ws + 65536);
    float* Vpk = (float*)(ws + 65536 + gpk_bytes);
    unsigned short* xin  = (unsigned short*)(ws + 65536 + gpk_bytes + vpk_bytes);
    unsigned char*  xin8 = (unsigned char*)((char*)xin + xin_bytes);
    unsigned short* gfi  = (unsigned short*)((char*)xin8 + x8_bytes);
    u64* xin8p = (u64*)(ws + base);

    k_prep<<<545, 256, 0, stream>>>(coeffs, coeffsB, G_cols, G_vals, EW, NS,
                                    Gpk, L_cols, L_vals, F2V_cols, F2V_vals,
                                    Vpk);
    k_transpose<<<641, 256, 0, stream>>>(x, xin, xin8, xin8p, tierA);
    if (tierA) {
        k_facegrad_p<<<NF / (4 * FPF), 256, 0, stream>>>(xin8p, Gpk, gfi);
    } else {
        k_facegrad_b<<<(NF / (4 * FPW)) * 8, 256, 0, stream>>>(xin8, Gpk, gfi);
    }
    k_vertex<<<((NV + VPB - 1) / VPB) * 8, 512, 0, stream>>>(
        xin, xin8, Vpk, gfi, coeffsB, bias, out);
}

// Round 10
// 342.473 us; speedup vs baseline: 1.3306x; 1.0578x over previous
//
#include <hip/hip_runtime.h>
#include <hip/hip_bf16.h>

typedef __hip_bfloat16 bf16;
typedef __attribute__((ext_vector_type(8))) short short8;
typedef __attribute__((ext_vector_type(4))) float floatx4;
typedef unsigned long long u64;

#define NVP 10242
#define NV  40962
#define NF  81920
#define VPB 32
#define FPW 4     // faces per wave in k_facegrad
#define NVB 1281  // ceil(NV/VPB)
#define TBLK 5128 // transpose blocks (641 v-groups x 8 batches)

__device__ __forceinline__ unsigned short f2bfbits(float f) {
    bf16 h = __float2bfloat16(f);
    return __builtin_bit_cast(unsigned short, h);
}
// fp8 e4m3 (OCP on gfx950)
__device__ __forceinline__ unsigned short pk_fp8(float a, float b) {
    int p = __builtin_amdgcn_cvt_pk_fp8_f32(a, b, 0, false);
    return (unsigned short)(p & 0xffff);
}
__device__ __forceinline__ unsigned char one_fp8(float a) {
    int p = __builtin_amdgcn_cvt_pk_fp8_f32(a, 0.f, 0, false);
    return (unsigned char)(p & 0xff);
}
__device__ __forceinline__ float f8s0(unsigned int u){return __builtin_amdgcn_cvt_f32_fp8(u,0);}
__device__ __forceinline__ float f8s1(unsigned int u){return __builtin_amdgcn_cvt_f32_fp8(u,1);}

// ---------------------------------------------------------------------------
// K0 (merged transpose + prep). Blocks [0,TBLK): per-batch transpose with
// batch = bid&7 == XCD (round-robin) -> xin8[b] written dirty into XCD b's
// L2, which k_facegrad batch b (also XCD b) then gathers as L2 hits.
// Blocks [TBLK, TBLK+545): prep (coeffsB / Gpk / Vpk), R4 form.
// Gpk per-face 128 B: dw[0..8] 9 cols | dw[16..24] 9 vals | dw[25..27] EW |
//                     dw[28..30] NS.
// Vpk per-vertex 112 B: dw[0..6] 7 Lcols | dw[7..12] 6 F2Vcols |
//                       dw[14..20] 7 Lvals | dw[21..26] 6 F2Vvals.
// ---------------------------------------------------------------------------
__global__ void __launch_bounds__(256) k_pt(
    const float* __restrict__ x,
    unsigned short* __restrict__ xin,
    unsigned char* __restrict__ xin8,
    const float* __restrict__ coeffs,
    unsigned short* __restrict__ coeffsB,
    const int* __restrict__ G_cols,
    const float* __restrict__ G_vals,
    const float* __restrict__ EW,
    const float* __restrict__ NS,
    float* __restrict__ Gpk,
    const int* __restrict__ L_cols,
    const float* __restrict__ L_vals,
    const int* __restrict__ F2V_cols,
    const float* __restrict__ F2V_vals,
    float* __restrict__ Vpk) {
    __shared__ float tile[64][65];
    int bid = blockIdx.x;
    if (bid < TBLK) {
        int batch = bid & 7;
        int v0    = (bid >> 3) * 64;
        const float* xb = x + (size_t)batch * 64 * NVP;
        unsigned short* xinb  = xin  + (size_t)batch * NV * 64;
        unsigned char*  xin8b = xin8 + (size_t)batch * NV * 64;
        int tx = threadIdx.x & 63;
        int ty = threadIdx.x >> 6;
        int v  = v0 + tx;
#pragma unroll
        for (int r = 0; r < 16; ++r) {
            int c = ty + r * 4;
            tile[tx][c] = (v < NVP) ? xb[c * NVP + v] : 1.0f;
        }
        __syncthreads();
#pragma unroll
        for (int r = 0; r < 16; ++r) {
            int vl = ty + r * 4;
            int vv = v0 + vl;
            if (vv < NV) {
                float val = tile[vl][tx];
                xinb [vv * 64 + tx] = f2bfbits(val);
                xin8b[vv * 64 + tx] = one_fp8(val);
            }
        }
        return;
    }
    int b = bid - TBLK;                                // 0..544
    if (b < 64) {
        int t = b * 256 + threadIdx.x;                 // 0..16383
        int j = t & 7, lane = (t >> 3) & 63, s = t >> 9;
        int ot = s >> 3, kk = s & 7;
        int o  = ot * 16 + (lane & 15);
        int kg = kk * 32 + (lane >> 4) * 8 + j;
        coeffsB[t] = f2bfbits(coeffs[o * 256 + kg]);
    } else if (b < 384) {
        int f = (b - 64) * 256 + threadIdx.x;          // NF/256 = 320 exact
        float r[32];
#pragma unroll
        for (int q = 0; q < 32; ++q) r[q] = 0.f;
#pragma unroll
        for (int d = 0; d < 3; ++d)
#pragma unroll
            for (int j = 0; j < 3; ++j) {
                int idx = (d * NF + f) * 3 + j;
                r[d * 3 + j]      = __int_as_float(G_cols[idx]);
                r[16 + d * 3 + j] = G_vals[idx];
            }
#pragma unroll
        for (int d = 0; d < 3; ++d) {
            r[25 + d] = EW[f * 3 + d];
            r[28 + d] = NS[f * 3 + d];
        }
        float4* dst = (float4*)(Gpk + (size_t)f * 32);
#pragma unroll
        for (int q = 0; q < 8; ++q) dst[q] = ((const float4*)r)[q];
    } else {
        int v = (b - 384) * 256 + threadIdx.x;
        if (v >= NV) return;
        float r[28];
#pragma unroll
        for (int q = 0; q < 28; ++q) r[q] = 0.f;
#pragma unroll
        for (int j = 0; j < 7; ++j) {
            r[j]      = __int_as_float(L_cols[v * 7 + j]);
            r[14 + j] = L_vals[v * 7 + j];
        }
#pragma unroll
        for (int j = 0; j < 6; ++j) {
            r[7 + j]  = __int_as_float(F2V_cols[v * 6 + j]);
            r[21 + j] = F2V_vals[v * 6 + j];
        }
        float4* dst = (float4*)(Vpk + (size_t)v * 28);
#pragma unroll
        for (int q = 0; q < 7; ++q) dst[q] = ((const float4*)r)[q];
    }
}

// ---------------------------------------------------------------------------
// K2: per-batch facegrad (R4 form, proven). batch = bid&7 == XCD; xin8[b]
// is dirty-resident in this XCD's L2 from k_pt. 3-stage SoA, 36 gathers.
// ---------------------------------------------------------------------------
__global__ void __launch_bounds__(256, 4) k_facegrad(
    const unsigned char* __restrict__ xin8,
    const float* __restrict__ Gpk,
    unsigned short* __restrict__ gfi) {
    int batch = blockIdx.x & 7;
    int fblk  = blockIdx.x >> 3;
    xin8 += (size_t)batch * 64 * NV;
    gfi  += (size_t)batch * 64 * NF;
    int w  = __builtin_amdgcn_readfirstlane(threadIdx.x >> 6);
    int c  = threadIdx.x & 63;
    int f0 = (fblk * 4 + w) * FPW;

    int gc[FPW][9];
#pragma unroll
    for (int i = 0; i < FPW; ++i) {
        const int* ri = (const int*)(Gpk + (size_t)(f0 + i) * 32);
#pragma unroll
        for (int j = 0; j < 9; ++j) gc[i][j] = ri[j];
    }
    unsigned int xv[FPW][9];
#pragma unroll
    for (int i = 0; i < FPW; ++i)
#pragma unroll
        for (int j = 0; j < 9; ++j)
            xv[i][j] = xin8[(size_t)gc[i][j] * 64 + c];
    __builtin_amdgcn_sched_barrier(0);
#pragma unroll
    for (int i = 0; i < FPW; ++i) {
        const float* rf = Gpk + (size_t)(f0 + i) * 32;
        float g0 = rf[16] * f8s0(xv[i][0]) + rf[17] * f8s0(xv[i][1])
                 + rf[18] * f8s0(xv[i][2]);
        float g1 = rf[19] * f8s0(xv[i][3]) + rf[20] * f8s0(xv[i][4])
                 + rf[21] * f8s0(xv[i][5]);
        float g2 = rf[22] * f8s0(xv[i][6]) + rf[23] * f8s0(xv[i][7])
                 + rf[24] * f8s0(xv[i][8]);
        float ew = g0 * rf[25] + g1 * rf[26] + g2 * rf[27];
        float ns = g0 * rf[28] + g1 * rf[29] + g2 * rf[30];
        gfi[(f0 + i) * 64 + c] = pk_fp8(ew, ns);
    }
}

// ---------------------------------------------------------------------------
// K3: vertex kernel, R4 structure (proven 91 µs). batch = bid&7 == XCD.
// KEEP_ALIVE=1 variant (B): after stage B, sched_barrier + keep-alive asm on
// all 56 staged gather results + sched_barrier -> forces RA to keep all 56
// loads in flight (VGPR=40 in A proves the scheduler otherwise serializes
// to ~14). A (groups [0,641)) is R4-exact; B covers groups [641,1281).
// ---------------------------------------------------------------------------
template <int KEEP_ALIVE>
__device__ __forceinline__ void vertex_body(
    const unsigned short* __restrict__ xin,
    const unsigned char* __restrict__ xin8,
    const float* __restrict__ Vpk,
    const unsigned short* __restrict__ gfi,
    const unsigned short* __restrict__ coeffsB,
    const float* __restrict__ bias,
    float* __restrict__ out, int vbBase) {
    int batch = blockIdx.x & 7;
    int vbIdx = vbBase + (blockIdx.x >> 3);
    int vb    = vbIdx * VPB;
    xin  += (size_t)batch * 64 * NV;
    xin8 += (size_t)batch * 64 * NV;
    gfi  += (size_t)batch * 64 * NF;
    out  += (size_t)batch * 64 * NV;

    __shared__ unsigned short feat[VPB * 264];   // 16896 B
    __shared__ float outs[VPB * 65];             // 8320 B
    int w    = __builtin_amdgcn_readfirstlane(threadIdx.x >> 6);  // 0..7
    int lane = threadIdx.x & 63;
    int c    = lane;

    int vcs[4];
#pragma unroll
    for (int i = 0; i < 4; ++i) {
        int v = vb + w * 4 + i;
        vcs[i] = __builtin_amdgcn_readfirstlane(v < NV ? v : NV - 1);
    }
    // stage A: scalar col loads
    int lc[4][7], fc[4][6];
#pragma unroll
    for (int i = 0; i < 4; ++i) {
        const int* ri = (const int*)(Vpk + (size_t)vcs[i] * 28);
#pragma unroll
        for (int j = 0; j < 7; ++j) lc[i][j] = ri[j];
#pragma unroll
        for (int j = 0; j < 6; ++j) fc[i][j] = ri[7 + j];
    }
    // stage B: issue ALL 56 vector gathers
    unsigned int f0u[4], xl[4][7], gg[4][6];
#pragma unroll
    for (int i = 0; i < 4; ++i) {
        f0u[i] = xin[(size_t)vcs[i] * 64 + c];
#pragma unroll
        for (int j = 0; j < 7; ++j)
            xl[i][j] = xin8[(size_t)lc[i][j] * 64 + c];
#pragma unroll
        for (int j = 0; j < 6; ++j)
            gg[i][j] = gfi[(size_t)fc[i][j] * 64 + c];
    }
    __builtin_amdgcn_sched_barrier(0);
    if (KEEP_ALIVE) {
#pragma unroll
        for (int i = 0; i < 4; ++i) {
            asm volatile("" :: "v"(f0u[i]));
#pragma unroll
            for (int j = 0; j < 7; ++j) asm volatile("" :: "v"(xl[i][j]));
#pragma unroll
            for (int j = 0; j < 6; ++j) asm volatile("" :: "v"(gg[i][j]));
        }
        __builtin_amdgcn_sched_barrier(0);
    }
    // stage C: val loads + math + feat store
#pragma unroll
    for (int i = 0; i < 4; ++i) {
        const float* rv = Vpk + (size_t)vcs[i] * 28;
        float lap = 0.f;
#pragma unroll
        for (int j = 0; j < 7; ++j)
            lap += rv[14 + j] * f8s0(xl[i][j]);
        float ew = 0.f, ns = 0.f;
#pragma unroll
        for (int j = 0; j < 6; ++j) {
            float val = rv[21 + j];
            ew += val * f8s0(gg[i][j]);
            ns += val * f8s1(gg[i][j]);
        }
        ushort4 p = make_ushort4((unsigned short)f0u[i], f2bfbits(lap),
                                 f2bfbits(ew), f2bfbits(ns));
        *(ushort4*)&feat[(w * 4 + i) * 264 + c * 4] = p;  // 8B, 2-way (free)
    }
    __syncthreads();

    // ---- phase 2: MFMA. wave w: o-tile = w&3, v-half = w>>2 ----
    int m = lane & 15, quad = lane >> 4;
    int ot = w & 3, vh = w >> 2;
    float bo = bias[ot * 16 + m];
    floatx4 acc = {bo, bo, bo, bo};
#pragma unroll
    for (int kk = 0; kk < 8; ++kk) {
        short8 a = *(const short8*)&feat[(vh * 16 + m) * 264 + kk * 32 + quad * 8];
        short8 bfr = *(const short8*)&coeffsB[((ot * 8 + kk) * 64 + lane) * 8];
        acc = __builtin_amdgcn_mfma_f32_16x16x32_bf16(a, bfr, acc, 0, 0, 0);
    }

    // ---- epilogue: C layout col=lane&15 (o), row=quad*4+reg (v) ----
#pragma unroll
    for (int r2 = 0; r2 < 4; ++r2)
        outs[(vh * 16 + quad * 4 + r2) * 65 + ot * 16 + m] = acc[r2];
    __syncthreads();
    int vp = threadIdx.x & 31;          // 32 consecutive v -> 128 B lines
    int og = threadIdx.x >> 5;          // 0..15
    if (vb + vp < NV) {
#pragma unroll
        for (int r2 = 0; r2 < 4; ++r2) {
            int o2 = og + r2 * 16;
            out[(size_t)o2 * NV + vb + vp] = outs[vp * 65 + o2];
        }
    }
}

__global__ void __launch_bounds__(512, 2) k_vertex_a(
    const unsigned short* __restrict__ xin,
    const unsigned char* __restrict__ xin8,
    const float* __restrict__ Vpk,
    const unsigned short* __restrict__ gfi,
    const unsigned short* __restrict__ coeffsB,
    const float* __restrict__ bias,
    float* __restrict__ out, int vbBase) {
    vertex_body<0>(xin, xin8, Vpk, gfi, coeffsB, bias, out, vbBase);
}

__global__ void __launch_bounds__(512, 2) k_vertex_b(
    const unsigned short* __restrict__ xin,
    const unsigned char* __restrict__ xin8,
    const float* __restrict__ Vpk,
    const unsigned short* __restrict__ gfi,
    const unsigned short* __restrict__ coeffsB,
    const float* __restrict__ bias,
    float* __restrict__ out, int vbBase) {
    vertex_body<1>(xin, xin8, Vpk, gfi, coeffsB, bias, out, vbBase);
}

// ---------------------------------------------------------------------------
extern "C" void kernel_launch(void* const* d_in, const int* in_sizes, int n_in,
                              void* d_out, int out_size, void* d_ws, size_t ws_size,
                              hipStream_t stream) {
    const float* x        = (const float*)d_in[0];
    const int*   G_cols   = (const int*)  d_in[2];
    const float* G_vals   = (const float*)d_in[3];
    const int*   L_cols   = (const int*)  d_in[5];
    const float* L_vals   = (const float*)d_in[6];
    const int*   F2V_cols = (const int*)  d_in[8];
    const float* F2V_vals = (const float*)d_in[9];
    const float* EW       = (const float*)d_in[10];
    const float* NS       = (const float*)d_in[11];
    const float* coeffs   = (const float*)d_in[12];
    const float* bias     = (const float*)d_in[13];
    float* out = (float*)d_out;

    char* ws = (char*)d_ws;
    const size_t gpk_bytes = (size_t)NF * 128;          // 10,485,760
    const size_t vpk_bytes = (size_t)NV * 112;          //  4,587,744
    const size_t xin_bytes = (size_t)8 * NV * 64 * 2;   // 41,945,088
    const size_t x8_bytes  = (size_t)8 * NV * 64;       // 20,972,544
    // gfi = 8*NF*64*2 = 83,886,080; total = 161,942,752 B (proven fit)

    unsigned short* coeffsB = (unsigned short*)ws;                    // 32 KB
    float* Gpk = (float*)(ws + 65536);
    float* Vpk = (float*)(ws + 65536 + gpk_bytes);
    unsigned short* xin  = (unsigned short*)(ws + 65536 + gpk_bytes + vpk_bytes);
    unsigned char*  xin8 = (unsigned char*)((char*)xin + xin_bytes);
    unsigned short* gfi  = (unsigned short*)((char*)xin8 + x8_bytes);

    k_pt<<<TBLK + 545, 256, 0, stream>>>(x, xin, xin8,
                                         coeffs, coeffsB, G_cols, G_vals,
                                         EW, NS, Gpk, L_cols, L_vals,
                                         F2V_cols, F2V_vals, Vpk);
    k_facegrad<<<(NF / (4 * FPW)) * 8, 256, 0, stream>>>(xin8, Gpk, gfi);
    // A/B within one run: A = R4-exact on vb-groups [0,641),
    // B = +keep-alive MLP on [641,1281). Both keep batch = bid&7 == XCD.
    k_vertex_a<<<641 * 8, 512, 0, stream>>>(xin, xin8, Vpk, gfi, coeffsB,
                                            bias, out, 0);
    k_vertex_b<<<640 * 8, 512, 0, stream>>>(xin, xin8, Vpk, gfi, coeffsB,
                                            bias, out, 641);
}